// Round 7
// baseline (4291.204 us; speedup 1.0000x reference)
//
#include <hip/hip_runtime.h>

// ---------------------------------------------------------------------------
// BasicModel_43387759624704: 2-layer GRU (T=512, B=256, H=512, COV=128),
// ragged masking, covariate head, exp(-dist) head. Inputs/outputs FLOAT32;
// MFMA operands bf16 in workspace, f32 accumulate/state.
//
// ROUND 14: fix R13's self-inflicted serial stall.
//  * scan_fused: x fragments double-buffered in REGISTERS (xa=cur, xn=next).
//    xn loads are issued BEFORE the exchange poll, so the poll's vmcnt wait
//    covers both concurrently (max, not sum). R13 issued them after the
//    publish -> every step opened with a ~700cy stall on its own x-loads.
//  * Everything else unchanged from R13 (sentinel dataflow, fused Wih GEMM,
//    preds, prep, dist).
// ---------------------------------------------------------------------------

typedef unsigned short u16;
typedef unsigned long long u64;
typedef __attribute__((ext_vector_type(8))) short short8;
typedef short8 bf16x8;
typedef __attribute__((ext_vector_type(4))) float f32x4;

#define T_DIM 512
#define B_DIM 256
#define H_DIM 512
#define G3H   1536
#define BT    131072        // 256*512
#define XPK   256           // padded K for layer-0 x (129 -> 256)
#define PRED_ELEMS 16875264 // 256*511*129

// async global->LDS, 16B per lane, wave-uniform LDS base (HW: base + lane*16)
#define GLD16(gp, lp) __builtin_amdgcn_global_load_lds( \
    (const __attribute__((address_space(1))) void*)(gp), \
    (__attribute__((address_space(3))) void*)(lp), 16, 0, 0)

__device__ __forceinline__ u16 f2bf(float f) {  // RNE
    union { float f; unsigned i; } v; v.f = f;
    unsigned i = v.i;
    return (u16)((i + 0x7FFFu + ((i >> 16) & 1u)) >> 16);
}
__device__ __forceinline__ float bf2f(u16 u) {
    union { unsigned i; float f; } v; v.i = ((unsigned)u) << 16; return v.f;
}
__device__ __forceinline__ float sigm(float x) { return 1.f / (1.f + __expf(-x)); }
__device__ __forceinline__ float tanh_f(float x) {
    float ax = fabsf(x);
    float e = __expf(-2.f * ax);
    float t = (1.f - e) / (1.f + e);
    return x < 0.f ? -t : t;
}
// coherent 16B load (2x relaxed agent atomics -> MALL coherence point)
__device__ __forceinline__ bf16x8 aload16(const u16* p) {
    union { bf16x8 v; u64 q[2]; } r;
    const u64* qp = (const u64*)p;
    r.q[0] = __hip_atomic_load(qp + 0, __ATOMIC_RELAXED, __HIP_MEMORY_SCOPE_AGENT);
    r.q[1] = __hip_atomic_load(qp + 1, __ATOMIC_RELAXED, __HIP_MEMORY_SCOPE_AGENT);
    return r.v;
}
// 1 if any of the 8 bf16 halves equals the sentinel
__device__ __forceinline__ unsigned chk8(bf16x8 v) {
    union { bf16x8 v; unsigned d[4]; } u; u.v = v;
    unsigned b = 0;
#pragma unroll
    for (int i = 0; i < 4; ++i) {
        unsigned d = u.d[i] ^ 0x7FC07FC0u;
        b |= (unsigned)((d & 0xFFFFu) == 0u) | (unsigned)((d >> 16) == 0u);
    }
    return b;
}

// ---------------------------------------------------------------------------
// One-dispatch preamble: weight conversions + o-chunk sentinel fill.
__global__ void prep_kernel(const float* __restrict__ Wih0, const float* __restrict__ Wih1,
                            const float* __restrict__ Whh0, const float* __restrict__ Whh1,
                            const float* __restrict__ h0,   const float* __restrict__ Wcov,
                            u16* __restrict__ wih0b, u16* __restrict__ wih1b,
                            u16* __restrict__ whh0b, u16* __restrict__ whh1b,
                            u16* __restrict__ h0bf,  u16* __restrict__ wcovb,
                            float* __restrict__ wlastf,
                            u16* __restrict__ o0c, u16* __restrict__ o1c, int TC) {
    const int gid = blockIdx.x * 256 + threadIdx.x;
    const int gsz = gridDim.x * 256;
    for (int i = gid; i < 128; i += gsz) wlastf[i] = Wcov[i * 513 + 512];
    for (int i = gid; i < 128 * 512; i += gsz) {
        int r = i >> 9, c = i & 511;
        wcovb[i] = f2bf(Wcov[r * 513 + c]);
    }
    for (int i = gid; i < 512 * 512; i += gsz) h0bf[i] = f2bf(h0[i]);
    for (int i = gid; i < 1536 * XPK; i += gsz) {
        int r = i >> 8, c = i & 255;
        wih0b[i] = f2bf(c < 129 ? Wih0[r * 129 + c] : 0.f);
    }
    for (int i = gid; i < 1536 * 512; i += gsz) wih1b[i] = f2bf(Wih1[i]);
    for (int i = gid; i < 1536 * 512; i += gsz) whh0b[i] = f2bf(Whh0[i]);
    for (int i = gid; i < 1536 * 512; i += gsz) whh1b[i] = f2bf(Whh1[i]);
    // sentinel fill (u64 stores)
    const u64 SQ = 0x7FC07FC07FC07FC0ULL;
    const size_t nq = (size_t)TC * BT / 4;
    u64* p0 = (u64*)o0c;
    u64* p1 = (u64*)o1c;
    for (size_t i = gid; i < nq; i += gsz) p0[i] = SQ;
    for (size_t i = gid; i < nq; i += gsz) p1[i] = SQ;
}

// multi-chunk fallback: re-sentinel an o-chunk between chunks
__global__ void sentinel_kernel(u16* __restrict__ buf, int TC) {
    const u64 SQ = 0x7FC07FC07FC07FC0ULL;
    const size_t nq = (size_t)TC * BT / 4;
    u64* p = (u64*)buf;
    const size_t gid = blockIdx.x * 256 + threadIdx.x;
    const size_t gsz = (size_t)gridDim.x * 256;
    for (size_t i = gid; i < nq; i += gsz) p[i] = SQ;
}

// x: f32 [rows][129] -> bf16 [rows][256] zero-padded (shifts only)
__global__ void cvt_pad_x_kernel(const float* __restrict__ src,
                                 u16* __restrict__ dst, int rows) {
    const int n = rows * 256;
    for (int idx = blockIdx.x * blockDim.x + threadIdx.x; idx < n;
         idx += gridDim.x * blockDim.x) {
        const int row = idx >> 8, col = idx & 255;
        float v = (col < 129) ? src[(size_t)row * 129 + col] : 0.f;
        dst[idx] = f2bf(v);
    }
}

// ---------------------------------------------------------------------------
// Fused input-GEMM + GRU scan. Grid (32 col-blocks, 16 row-groups) = 512
// blocks = 2/CU. Per step: x-MFMAs (xa regs) -> issue xn prefetch -> h poll
// -> h-MFMAs -> P reduce -> gates -> publish -> swap xa<-xn.
// AK = xin K-dim (256 for layer0, 512 for layer1).
template<int AK>
__global__ __launch_bounds__(256, 2) void scan_fused_kernel(
    const u16* __restrict__ xin,     // [TC][256][AK] bf16 (x-pad or o0)
    const u16* __restrict__ Wih,     // [1536][AK] bf16
    const float* __restrict__ bih,   // [1536] f32
    const u16* __restrict__ Whh,     // [1536][512] bf16
    const float* __restrict__ bhh,   // [1536] f32
    const int* __restrict__ lengths, // [256]
    const float* __restrict__ h0l,   // [256][512] f32 (layer slice)
    const u16* __restrict__ h0bfl,   // [256][512] bf16 (layer slice)
    u16* __restrict__ o,             // [TC][256][512]: output AND exchange
    u16* __restrict__ hcarry,        // [256][512] bf16 cross-chunk carry
    float* __restrict__ hlast,       // [256][512] f32 carry (layer slice)
    int t0, int TC) {
    __shared__ __attribute__((aligned(16))) u16 Wl[48 * 520];
    __shared__ __attribute__((aligned(16))) float P[16 * 256];
    __shared__ __attribute__((aligned(16))) float bRZ[32], bNX[16], bNH[16];
    const int tid = threadIdx.x, lane = tid & 63, w = tid >> 6;
    const int n0 = blockIdx.x * 16, b0 = blockIdx.y * 16;
    const int am = lane & 15, aq = lane >> 4;
    constexpr int KW = AK / 4;       // per-wave x K-range
    constexpr int KB2 = KW / 32;     // x kb count (2 or 4)
    // one-time: stage Whh slice into LDS (rows: 3 gates x 16 cols, K=512)
#pragma unroll
    for (int it = 0; it < 12; ++it) {
        int f = it * 2048 + tid * 8;
        int j = f >> 9, k = f & 511;
        *(short8*)&Wl[j * 520 + k] =
            *(const short8*)(Whh + ((size_t)((j >> 4) * 512 + n0 + (j & 15))) * 512 + k);
    }
    if (tid < 32) bRZ[tid] = bih[(tid >> 4) * 512 + n0 + (tid & 15)] +
                             bhh[(tid >> 4) * 512 + n0 + (tid & 15)];
    else if (tid < 48) bNX[tid - 32] = bih[1024 + n0 + (tid - 32)];
    else if (tid < 64) bNH[tid - 48] = bhh[1024 + n0 + (tid - 48)];
    // register-resident Wih fragments: 3 gates x KB2
    bf16x8 wf[3][KB2];
#pragma unroll
    for (int g = 0; g < 3; ++g)
#pragma unroll
        for (int kb = 0; kb < KB2; ++kb)
            wf[g][kb] = *(const short8*)(Wih +
                (size_t)(g * 512 + n0 + am) * AK + w * KW + kb * 32 + aq * 8);
    const int m = tid >> 4, c = tid & 15;
    const int b = b0 + m, col = n0 + c;
    float h = (t0 == 0) ? h0l[(size_t)b * 512 + col]
                        : hlast[(size_t)b * 512 + col];
    const int len = lengths[b];
    // prefetch step-0 x fragments
    bf16x8 xa[KB2], xn[KB2];
#pragma unroll
    for (int kb = 0; kb < KB2; ++kb)
        xa[kb] = *(const short8*)(xin + (size_t)(b0 + am) * AK + w * KW + kb * 32 + aq * 8);
    __syncthreads();
    for (int tl = 0; tl < TC; ++tl) {
        const int t = t0 + tl;
        // --- x-part MFMAs (consume xa; independent of the exchange) ---
        f32x4 ar = {}, az = {}, anx = {}, anh = {};
#pragma unroll
        for (int kb = 0; kb < KB2; ++kb) {
            ar  = __builtin_amdgcn_mfma_f32_16x16x32_bf16(xa[kb], wf[0][kb], ar, 0, 0, 0);
            az  = __builtin_amdgcn_mfma_f32_16x16x32_bf16(xa[kb], wf[1][kb], az, 0, 0, 0);
            anx = __builtin_amdgcn_mfma_f32_16x16x32_bf16(xa[kb], wf[2][kb], anx, 0, 0, 0);
        }
        // --- issue NEXT step's x loads BEFORE the poll: their latency rides
        //     under the poll's vmcnt wait (max, not sum)  [R14 fix] ---
        if (tl < TC - 1) {
#pragma unroll
            for (int kb = 0; kb < KB2; ++kb)
                xn[kb] = *(const short8*)(xin +
                    ((size_t)(tl + 1) * 256 + b0 + am) * AK + w * KW + kb * 32 + aq * 8);
        }
        // --- h exchange (sentinel-dataflow, R12) ---
        const u16* Asrc = (tl == 0) ? ((t0 == 0) ? h0bfl : hcarry)
                                    : (o + (size_t)(tl - 1) * BT);
        const u16* arow = Asrc + (size_t)(b0 + am) * 512 + w * 128 + aq * 8;
        bf16x8 av[4];
        if (tl == 0) {   // clean source (earlier dispatch), no sentinel check
            av[0] = aload16(arow);      av[1] = aload16(arow + 32);
            av[2] = aload16(arow + 64); av[3] = aload16(arow + 96);
        } else {
            for (;;) {
                av[0] = aload16(arow);
                if (!__any((int)chk8(av[0]))) break;
                __builtin_amdgcn_s_sleep(1);
            }
            for (;;) {
                av[1] = aload16(arow + 32);
                av[2] = aload16(arow + 64);
                av[3] = aload16(arow + 96);
                if (!__any((int)(chk8(av[1]) | chk8(av[2]) | chk8(av[3])))) break;
                __builtin_amdgcn_s_sleep(1);
            }
        }
        // --- h-part MFMAs ---
#pragma unroll
        for (int kb = 0; kb < 4; ++kb) {
            const int k = w * 128 + kb * 32 + aq * 8;
            bf16x8 wr = *(short8*)&Wl[(0 + am) * 520 + k];
            bf16x8 wz = *(short8*)&Wl[(16 + am) * 520 + k];
            bf16x8 wn = *(short8*)&Wl[(32 + am) * 520 + k];
            ar  = __builtin_amdgcn_mfma_f32_16x16x32_bf16(av[kb], wr, ar, 0, 0, 0);
            az  = __builtin_amdgcn_mfma_f32_16x16x32_bf16(av[kb], wz, az, 0, 0, 0);
            anh = __builtin_amdgcn_mfma_f32_16x16x32_bf16(av[kb], wn, anh, 0, 0, 0);
        }
#pragma unroll
        for (int r = 0; r < 4; ++r) {
            P[(w * 4 + 0) * 256 + (aq * 4 + r) * 16 + am] = ar[r];
            P[(w * 4 + 1) * 256 + (aq * 4 + r) * 16 + am] = az[r];
            P[(w * 4 + 2) * 256 + (aq * 4 + r) * 16 + am] = anx[r];
            P[(w * 4 + 3) * 256 + (aq * 4 + r) * 16 + am] = anh[r];
        }
        __syncthreads();                              // (A) P visible
        float Cr = bRZ[c], Cz = bRZ[16 + c], Nx = bNX[c], Nh = bNH[c];
#pragma unroll
        for (int w2 = 0; w2 < 4; ++w2) {
            Cr += P[(w2 * 4 + 0) * 256 + tid];
            Cz += P[(w2 * 4 + 1) * 256 + tid];
            Nx += P[(w2 * 4 + 2) * 256 + tid];
            Nh += P[(w2 * 4 + 3) * 256 + tid];
        }
        __syncthreads();                              // (B) P consumed; next
                                                      // write is post-barrier
        float r_ = sigm(Cr);
        float z_ = sigm(Cz);
        float n_ = tanh_f(Nx + r_ * Nh);
        float hnew = (1.f - z_) * n_ + z_ * h;
        h = (t < len) ? hnew : h;    // freeze past length
        // publish o[tl] = frozen h (output AND exchange; masked downstream)
        unsigned hb = (unsigned)f2bf(h);
        unsigned part = hb | ((unsigned)__shfl_down((int)hb, 1) << 16);
        unsigned hi2 = (unsigned)__shfl_down((int)part, 2);
        if ((lane & 3) == 0) {
            u64 q = (u64)part | ((u64)hi2 << 32);
            const int mrow = w * 4 + (lane >> 4);
            const int cg = lane & 15;      // 0,4,8,12
            __hip_atomic_store(
                (u64*)(o + (size_t)tl * BT + (size_t)(b0 + mrow) * 512 + n0 + cg),
                q, __ATOMIC_RELAXED, __HIP_MEMORY_SCOPE_AGENT);
        }
        if (tl < TC - 1) {
            // swap: next step consumes xn (loads long since landed)
#pragma unroll
            for (int kb = 0; kb < KB2; ++kb) xa[kb] = xn[kb];
        } else {
            // cross-chunk / cross-launch carries (plain stores, stream order)
            hcarry[(size_t)b * 512 + col] = f2bf(h);
            hlast[(size_t)b * 512 + col] = h;
        }
    }
}

// ---------------------------------------------------------------------------
// preds as a 128x128 GEMM (N=128 -> one col-block) with fused epilogue:
// out[b][t][c] = mask * (acc + b_cov[c] + x[t,b,0]*wlast[c]); channel 128
// zeroed. o1c rows past len hold frozen h; the t < len-1 mask here matches
// the reference, so outputs are identical. 2-phase dbuf staging.
__global__ __launch_bounds__(256) void preds_kernel(
    const u16* __restrict__ o1c, const u16* __restrict__ WcovBf,
    const float* __restrict__ wlastf, const float* __restrict__ bcov,
    const float* __restrict__ x, const int* __restrict__ lengths,
    float* __restrict__ out, int t0) {
    __shared__ __attribute__((aligned(16))) u16 Sh[2][16384];
    const int tid = threadIdx.x, lane = tid & 63, w = tid >> 6;
    const int m0 = blockIdx.x * 128;
    const int r0 = (w & 1) * 64, c0 = (w >> 1) * 64;
    const int am = lane & 15, aq = lane >> 4;
    const int l8 = lane >> 3, lc = lane & 7;
    const int swz = (lc ^ l8) << 3;
    f32x4 acc[4][4] = {};
#pragma unroll
    for (int s = 0; s < 4; ++s) {
        const int i = w * 4 + s, row = i * 8 + l8;
        GLD16(o1c + (size_t)(m0 + row) * 512 + swz, &Sh[0][i * 512]);
        GLD16(WcovBf + (size_t)row * 512 + swz, &Sh[0][8192 + i * 512]);
    }
    __syncthreads();
    int cur = 0;
    for (int kt = 0; kt < 8; ++kt) {
        if (kt + 1 < 8) {
            const int kb = (kt + 1) << 6;
#pragma unroll
            for (int s = 0; s < 4; ++s) {
                const int i = w * 4 + s, row = i * 8 + l8;
                GLD16(o1c + (size_t)(m0 + row) * 512 + kb + swz,
                      &Sh[cur ^ 1][i * 512]);
                GLD16(WcovBf + (size_t)row * 512 + kb + swz,
                      &Sh[cur ^ 1][8192 + i * 512]);
            }
        }
        const u16* Ash = &Sh[cur][0];
        const u16* Bsh = &Sh[cur][8192];
#pragma unroll
        for (int ks = 0; ks < 2; ++ks) {
            bf16x8 a[4], bb[4];
#pragma unroll
            for (int f = 0; f < 4; ++f) {
                const int ar2 = r0 + f * 16 + am;
                a[f] = *(short8*)&Ash[ar2 * 64 + (((ks * 4 + aq) ^ (ar2 & 7)) << 3)];
            }
#pragma unroll
            for (int f = 0; f < 4; ++f) {
                const int br = c0 + f * 16 + am;
                bb[f] = *(short8*)&Bsh[br * 64 + (((ks * 4 + aq) ^ (br & 7)) << 3)];
            }
#pragma unroll
            for (int fi = 0; fi < 4; ++fi)
#pragma unroll
                for (int fj = 0; fj < 4; ++fj)
                    acc[fi][fj] = __builtin_amdgcn_mfma_f32_16x16x32_bf16(
                        a[fi], bb[fj], acc[fi][fj], 0, 0, 0);
        }
        __syncthreads();
        cur ^= 1;
    }
    const int tl = m0 >> 8;     // one tl per block (128 rows = half of a tl)
    const int t = t0 + tl;
    if (t < 511) {
#pragma unroll
        for (int fj = 0; fj < 4; ++fj) {
            const int cc = c0 + fj * 16 + am;
            const float bc = bcov[cc], wl = wlastf[cc];
#pragma unroll
            for (int fi = 0; fi < 4; ++fi) {
#pragma unroll
                for (int r = 0; r < 4; ++r) {
                    const int row = m0 + r0 + fi * 16 + aq * 4 + r;
                    const int b = row & 255;
                    const bool valid = t < lengths[b] - 1;
                    const float tim = x[(size_t)t * (256 * 129) + b * 129];
                    out[(size_t)b * (511 * 129) + (size_t)t * 129 + cc] =
                        valid ? acc[fi][fj][r] + bc + tim * wl : 0.f;
                }
            }
        }
        if (tid < 128)  // channel 128 is always zero
            out[(size_t)((m0 & 255) + tid) * (511 * 129) + (size_t)t * 129 + 128] = 0.f;
    }
}

// ---------------------------------------------------------------------------
// dist[i][p] = exp(-(last_flat[i] @ W_par[p] + b_par[p])), f32 out.
__global__ void dist_kernel(const float* __restrict__ hl0,
                            const float* __restrict__ hl1,
                            const float* __restrict__ Wpar,
                            const float* __restrict__ bpar, float* __restrict__ out) {
    const int w = threadIdx.x >> 6, lane = threadIdx.x & 63;
    const float bp0 = bpar[0], bp1 = bpar[1];
    for (int rr = 0; rr < 8; ++rr) {
        const int i = (blockIdx.x * 4 + w) * 8 + rr;
        const int l = i >> 7, bb = (2 * i) & 255;
        const float* base = (l ? hl1 : hl0) + (size_t)bb * 512;
        float a0 = 0.f, a1 = 0.f;
#pragma unroll
        for (int cc = 0; cc < 16; ++cc) {
            const int k = cc * 64 + lane;
            const float v = base[k];
            a0 += v * Wpar[k];
            a1 += v * Wpar[1024 + k];
        }
#pragma unroll
        for (int off = 32; off; off >>= 1) {
            a0 += __shfl_down(a0, off);
            a1 += __shfl_down(a1, off);
        }
        if (lane == 0) {
            out[PRED_ELEMS + i * 2 + 0] = __expf(-(a0 + bp0));
            out[PRED_ELEMS + i * 2 + 1] = __expf(-(a1 + bp1));
        }
    }
}

// ---------------------------------------------------------------------------
extern "C" void kernel_launch(void* const* d_in, const int* in_sizes, int n_in,
                              void* d_out, int out_size, void* d_ws, size_t ws_size,
                              hipStream_t stream) {
    const float* x    = (const float*)d_in[0];
    const int* lens   = (const int*)d_in[1];
    const float* h0   = (const float*)d_in[2];
    const float* Wih0 = (const float*)d_in[3];
    const float* Whh0 = (const float*)d_in[4];
    const float* bih0 = (const float*)d_in[5];
    const float* bhh0 = (const float*)d_in[6];
    const float* Wih1 = (const float*)d_in[7];
    const float* Whh1 = (const float*)d_in[8];
    const float* bih1 = (const float*)d_in[9];
    const float* bhh1 = (const float*)d_in[10];
    const float* Wcov = (const float*)d_in[11];
    const float* bcov = (const float*)d_in[12];
    const float* Wpar = (const float*)d_in[13];
    const float* bpar = (const float*)d_in[14];
    float* out = (float*)d_out;
    char* wsb = (char*)d_ws;

    size_t off = 0;
    auto take = [&](size_t bytes) -> size_t {
        size_t r = off; off += (bytes + 255) & ~(size_t)255; return r;
    };
    const size_t oHl0   = take((size_t)BT * 4);         // layer0 f32 carry
    const size_t oHl1   = take((size_t)BT * 4);         // layer1 f32 carry
    const size_t oHc0   = take((size_t)BT * 2);         // layer0 bf16 chunk carry
    const size_t oHc1   = take((size_t)BT * 2);         // layer1 bf16 chunk carry
    const size_t oH0bf  = take((size_t)2 * BT * 2);     // bf16(h0) both layers
    const size_t oWih0b = take((size_t)G3H * XPK * 2);
    const size_t oWih1b = take((size_t)G3H * 512 * 2);
    const size_t oWhh0b = take((size_t)G3H * 512 * 2);
    const size_t oWhh1b = take((size_t)G3H * 512 * 2);
    const size_t oWcovb = take((size_t)128 * 512 * 2);
    const size_t oWlast = take(512);
    const size_t fixed = off;

    const size_t per = (size_t)256 * XPK * 2 +          // xbf chunk row
                       2 * (size_t)256 * 512 * 2 + 2048; // o0 + o1
    const size_t remain = ws_size > fixed ? ws_size - fixed : 0;
    int TC = 1;
    const int cands[10] = {512, 256, 128, 64, 32, 16, 8, 4, 2, 1};
    for (int i = 0; i < 10; ++i)
        if ((size_t)cands[i] * per <= remain) { TC = cands[i]; break; }

    const size_t oXbf = take((size_t)TC * 256 * XPK * 2);
    const size_t oO0  = take((size_t)TC * 256 * 512 * 2);
    const size_t oO1  = take((size_t)TC * 256 * 512 * 2);

    float* hl0  = (float*)(wsb + oHl0);
    float* hl1  = (float*)(wsb + oHl1);
    u16* hcar0  = (u16*)(wsb + oHc0);
    u16* hcar1  = (u16*)(wsb + oHc1);
    u16* h0bf   = (u16*)(wsb + oH0bf);
    u16* wih0b  = (u16*)(wsb + oWih0b);
    u16* wih1b  = (u16*)(wsb + oWih1b);
    u16* whh0b  = (u16*)(wsb + oWhh0b);
    u16* whh1b  = (u16*)(wsb + oWhh1b);
    u16* wcovb  = (u16*)(wsb + oWcovb);
    float* wlastf = (float*)(wsb + oWlast);
    u16* xbfc   = (u16*)(wsb + oXbf);
    u16* o0c    = (u16*)(wsb + oO0);
    u16* o1c    = (u16*)(wsb + oO1);

    prep_kernel<<<1024, 256, 0, stream>>>(Wih0, Wih1, Whh0, Whh1, h0, Wcov,
                                          wih0b, wih1b, whh0b, whh1b, h0bf,
                                          wcovb, wlastf, o0c, o1c, TC);

    for (int t0 = 0; t0 < T_DIM; t0 += TC) {
        int n = TC * 256 * XPK;
        int pg = (n + 255) / 256; if (pg > 2048) pg = 2048;
        cvt_pad_x_kernel<<<pg, 256, 0, stream>>>(
            x + (size_t)t0 * 256 * 129, xbfc, TC * 256);
        if (t0 > 0)   // multi-chunk fallback: re-arm sentinels
            sentinel_kernel<<<2048, 256, 0, stream>>>(o0c, TC);
        scan_fused_kernel<XPK><<<dim3(32, 16), 256, 0, stream>>>(
            xbfc, wih0b, bih0, whh0b, bhh0, lens, h0, h0bf,
            o0c, hcar0, hl0, t0, TC);
        if (t0 > 0)
            sentinel_kernel<<<2048, 256, 0, stream>>>(o1c, TC);
        scan_fused_kernel<512><<<dim3(32, 16), 256, 0, stream>>>(
            o0c, wih1b, bih1, whh1b, bhh1, lens, h0 + (size_t)BT,
            h0bf + (size_t)BT, o1c, hcar1, hl1, t0, TC);
        preds_kernel<<<dim3(TC * 2), 256, 0, stream>>>(
            o1c, wcovb, wlastf, bcov, x, lens, out, t0);
    }
    dist_kernel<<<8, 256, 0, stream>>>(hl0, hl1, Wpar, bpar, out);
}